// Round 1
// baseline (244.074 us; speedup 1.0000x reference)
//
#include <hip/hip_runtime.h>

// PSROIPool (R-FCN position-sensitive ROI pooling), K=7, H=W=1024.
// x: (49, 1024, 1024) fp32 score map; region: (4,) fp32 ijhw fractional.
// Output: scalar fp32 = mean over 49 bins of per-bin spatial mean.
//
// Key insight: the reference's dense einsum over (k,k,H,W) with separable 0/1
// masks is equivalent to summing, per bin (i,j), channel c=i*7+j over rows
// [floor(ri0), ceil(ri1)) x cols [floor(rj0), ceil(rj1)) -- ~88x88 pixels.
// Total traffic ~1.5 MB instead of 196 MB.

#define KK 7
#define HH 1024
#define WW 1024

__global__ __launch_bounds__(256) void psroi_bin_kernel(
    const float* __restrict__ x,
    const float* __restrict__ region,
    float* __restrict__ ws)
{
#pragma clang fp contract(off)
    const int b  = blockIdx.x;          // bin index 0..48
    const int bi = b / KK;
    const int bj = b - bi * KK;

    // Replicate reference fp32 arithmetic (no fma contraction):
    //   i0 = i - h/2; i1 = i + h/2
    //   ic = linspace(i0, i1, k+2)[1:-1]  ->  ic_t = i0 + t*delta, t=1..k
    //   delta = (i1 - i0) / (k+1)
    //   bh/2 = (h/k)/2
    const float ci = region[0];
    const float cj = region[1];
    const float h  = region[2];
    const float w  = region[3];

    const float i0  = ci - h / 2.0f;
    const float i1f = ci + h / 2.0f;
    const float j0  = cj - w / 2.0f;
    const float j1f = cj + w / 2.0f;

    const float di = (i1f - i0) / (float)(KK + 1);
    const float dj = (j1f - j0) / (float)(KK + 1);

    const float ic = i0 + (float)(bi + 1) * di;
    const float jc = j0 + (float)(bj + 1) * dj;

    const float bh2 = (h / (float)KK) / 2.0f;
    const float bw2 = (w / (float)KK) / 2.0f;

    // Integer pixel extents (mask semantics: r >= floor(lo) && r < ceil(hi),
    // with r in [0, H) -- clamping reproduces the arange-bounded mask).
    int r0 = (int)floorf((ic - bh2) * (float)HH);
    int r1 = (int)ceilf ((ic + bh2) * (float)HH);
    int c0 = (int)floorf((jc - bw2) * (float)WW);
    int c1 = (int)ceilf ((jc + bw2) * (float)WW);
    r0 = max(0, r0);  r1 = min(HH, r1);
    c0 = max(0, c0);  c1 = min(WW, c1);

    const int nr = max(0, r1 - r0);
    const int nc = max(0, c1 - c0);
    const int n  = nr * nc;

    const float* __restrict__ xc = x + (size_t)b * (size_t)(HH * WW);

    // Flattened grid-stride sum over the bin window (~7.9K elements).
    float acc = 0.0f;
    for (int idx = threadIdx.x; idx < n; idx += 256) {
        const int r = idx / nc;            // nc ~88; few iterations total
        const int c = idx - r * nc;
        acc += xc[(size_t)(r0 + r) * WW + (size_t)(c0 + c)];
    }

    // Wave64 shfl reduction, then cross-wave via LDS.
    #pragma unroll
    for (int off = 32; off > 0; off >>= 1)
        acc += __shfl_down(acc, off, 64);

    __shared__ float wsum[4];
    const int lane = threadIdx.x & 63;
    const int wid  = threadIdx.x >> 6;
    if (lane == 0) wsum[wid] = acc;
    __syncthreads();

    if (threadIdx.x == 0) {
        const float s = (wsum[0] + wsum[1]) + (wsum[2] + wsum[3]);
        ws[b] = s / (float)n;              // per-bin spatial mean (0/0 -> NaN, matches ref)
    }
}

__global__ __launch_bounds__(64) void psroi_final_kernel(
    const float* __restrict__ ws,
    float* __restrict__ out)
{
    const int t = threadIdx.x;
    float v = (t < KK * KK) ? ws[t] : 0.0f;
    #pragma unroll
    for (int off = 32; off > 0; off >>= 1)
        v += __shfl_down(v, off, 64);
    if (t == 0) out[0] = v / (float)(KK * KK);
}

extern "C" void kernel_launch(void* const* d_in, const int* in_sizes, int n_in,
                              void* d_out, int out_size, void* d_ws, size_t ws_size,
                              hipStream_t stream) {
    const float* x      = (const float*)d_in[0];   // (49, 1024, 1024) fp32
    const float* region = (const float*)d_in[1];   // (4,) fp32
    float* out = (float*)d_out;                    // 1 fp32 scalar
    float* ws  = (float*)d_ws;                     // >= 49 floats of scratch

    psroi_bin_kernel<<<KK * KK, 256, 0, stream>>>(x, region, ws);
    psroi_final_kernel<<<1, 64, 0, stream>>>(ws, out);
}

// Round 2
// 235.411 us; speedup vs baseline: 1.0368x; 1.0368x over previous
//
#include <hip/hip_runtime.h>

// PSROIPool (R-FCN), K=7, H=W=1024, fp32.
// Reference's dense masked einsum == per-bin window sum:
//   bin (i,j) reads channel c=i*7+j over rows [floor(ri0),ceil(ri1)) x
//   cols [floor(rj0),ceil(rj1)) (~88x88 px). ~1.5 MB total traffic vs 196 MB.
//
// Stage A: 196 blocks (49 bins x 4 row-interleaved parts) -> partial sums.
// Stage B: 1 wave reduces partials, divides by per-bin count, means over bins.

#define KK 7
#define HH 1024
#define WW 1024

struct Ext { int r0, r1, c0, c1; };

// Replicates the reference fp32 arithmetic exactly (absmax was 0.0 in R1).
// contract(off): prevent fma-contraction of i0 + t*delta perturbing floor/ceil.
__device__ __forceinline__ Ext bin_extent(const float* __restrict__ region,
                                          int bi, int bj) {
#pragma clang fp contract(off)
    const float ci = region[0];
    const float cj = region[1];
    const float h  = region[2];
    const float w  = region[3];

    const float i0  = ci - h / 2.0f;
    const float i1f = ci + h / 2.0f;
    const float j0  = cj - w / 2.0f;
    const float j1f = cj + w / 2.0f;

    const float di = (i1f - i0) / (float)(KK + 1);
    const float dj = (j1f - j0) / (float)(KK + 1);

    const float ic = i0 + (float)(bi + 1) * di;
    const float jc = j0 + (float)(bj + 1) * dj;

    const float bh2 = (h / (float)KK) / 2.0f;
    const float bw2 = (w / (float)KK) / 2.0f;

    Ext e;
    e.r0 = max(0, (int)floorf((ic - bh2) * (float)HH));
    e.r1 = min(HH, (int)ceilf ((ic + bh2) * (float)HH));
    e.c0 = max(0, (int)floorf((jc - bw2) * (float)WW));
    e.c1 = min(WW, (int)ceilf ((jc + bw2) * (float)WW));
    return e;
}

__global__ __launch_bounds__(256) void psroi_partial_kernel(
    const float* __restrict__ x,
    const float* __restrict__ region,
    float* __restrict__ ws)
{
    const int blk  = blockIdx.x;        // 0..195
    const int b    = blk >> 2;          // bin 0..48
    const int part = blk & 3;           // row-interleave part 0..3
    const int bi   = b / KK;
    const int bj   = b - bi * KK;

    const Ext e  = bin_extent(region, bi, bj);
    const int nc = e.c1 - e.c0;

    const float* __restrict__ xc = x + (size_t)b * (size_t)(HH * WW);

    const int lane = threadIdx.x & 63;
    const int wid  = threadIdx.x >> 6;

    // Rows for this (part, wave): r0 + part + 4*wid, stepping by 16.
    // Lanes cover columns c0+lane, c0+64+lane, ... (coalesced, no divides).
    float acc = 0.0f;
    for (int r = e.r0 + part + 4 * wid; r < e.r1; r += 16) {
        const float* __restrict__ row = xc + (size_t)r * WW + e.c0;
        for (int c = lane; c < nc; c += 64)
            acc += row[c];
    }

    #pragma unroll
    for (int off = 32; off > 0; off >>= 1)
        acc += __shfl_down(acc, off, 64);

    __shared__ float wsum[4];
    if (lane == 0) wsum[wid] = acc;
    __syncthreads();

    if (threadIdx.x == 0)
        ws[blk] = (wsum[0] + wsum[1]) + (wsum[2] + wsum[3]);
}

__global__ __launch_bounds__(64) void psroi_final_kernel(
    const float* __restrict__ region,
    const float* __restrict__ ws,
    float* __restrict__ out)
{
    const int t = threadIdx.x;
    float mean = 0.0f;
    if (t < KK * KK) {
        const int bi = t / KK;
        const int bj = t - bi * KK;
        const Ext e = bin_extent(region, bi, bj);
        const int n = (e.r1 - e.r0) * (e.c1 - e.c0);
        const float s = (ws[4 * t] + ws[4 * t + 1]) + (ws[4 * t + 2] + ws[4 * t + 3]);
        mean = s / (float)n;            // per-bin spatial mean
    }
    #pragma unroll
    for (int off = 32; off > 0; off >>= 1)
        mean += __shfl_down(mean, off, 64);
    if (t == 0) out[0] = mean / (float)(KK * KK);
}

extern "C" void kernel_launch(void* const* d_in, const int* in_sizes, int n_in,
                              void* d_out, int out_size, void* d_ws, size_t ws_size,
                              hipStream_t stream) {
    const float* x      = (const float*)d_in[0];   // (49, 1024, 1024) fp32
    const float* region = (const float*)d_in[1];   // (4,) fp32
    float* out = (float*)d_out;                    // scalar fp32
    float* ws  = (float*)d_ws;                     // uses 196 floats

    psroi_partial_kernel<<<KK * KK * 4, 256, 0, stream>>>(x, region, ws);
    psroi_final_kernel<<<1, 64, 0, stream>>>(region, ws, out);
}

// Round 3
// 230.995 us; speedup vs baseline: 1.0566x; 1.0191x over previous
//
#include <hip/hip_runtime.h>

// PSROIPool (R-FCN), K=7, H=W=1024, fp32.
// Per-bin window sum (bin (i,j) reads channel c=i*7+j over ~88x88 px),
// ~1.5 MB actual traffic vs the reference's 196 MB dense einsum.
//
// Stage A: 196 blocks (49 bins x 4 row-parts). Each half-wave (32 lanes)
//   covers one full row with a single float4 load (aligned window + column
//   mask); 3 predicated sweeps cover all rows -> 3 independent 16B
//   loads/lane, one latency exposure.
// Stage B: 1 wave reduces partials -> per-bin means -> scalar.

#define KK 7
#define HH 1024
#define WW 1024

struct Ext { int r0, r1, c0, c1; };

// Replicates reference fp32 arithmetic exactly (absmax 0.0 in R1/R2).
// contract(off): no fma-contraction of i0 + t*delta near floor/ceil edges.
__device__ __forceinline__ Ext bin_extent(const float* __restrict__ region,
                                          int bi, int bj) {
#pragma clang fp contract(off)
    const float ci = region[0];
    const float cj = region[1];
    const float h  = region[2];
    const float w  = region[3];

    const float i0  = ci - h / 2.0f;
    const float i1f = ci + h / 2.0f;
    const float j0  = cj - w / 2.0f;
    const float j1f = cj + w / 2.0f;

    const float di = (i1f - i0) / (float)(KK + 1);
    const float dj = (j1f - j0) / (float)(KK + 1);

    const float ic = i0 + (float)(bi + 1) * di;
    const float jc = j0 + (float)(bj + 1) * dj;

    const float bh2 = (h / (float)KK) / 2.0f;
    const float bw2 = (w / (float)KK) / 2.0f;

    Ext e;
    e.r0 = max(0, (int)floorf((ic - bh2) * (float)HH));
    e.r1 = min(HH, (int)ceilf ((ic + bh2) * (float)HH));
    e.c0 = max(0, (int)floorf((jc - bw2) * (float)WW));
    e.c1 = min(WW, (int)ceilf ((jc + bw2) * (float)WW));
    return e;
}

__global__ __launch_bounds__(256) void psroi_partial_kernel(
    const float* __restrict__ x,
    const float* __restrict__ region,
    float* __restrict__ ws)
{
    const int blk  = blockIdx.x;        // 0..195
    const int b    = blk >> 2;          // bin 0..48
    const int part = blk & 3;           // row part 0..3
    const int bi   = b / KK;
    const int bj   = b - bi * KK;

    const Ext e   = bin_extent(region, bi, bj);
    const int c0a = e.c0 & ~3;                    // 16B-aligned window start
    const int nq  = (e.c1 - c0a + 3) >> 2;        // quads per row (<=24 here)

    const int lane = threadIdx.x & 63;
    const int wid  = threadIdx.x >> 6;
    const int q    = lane & 31;                   // quad index within row
    const int half = lane >> 5;                   // which row of the pair

    const float* __restrict__ xc = x + (size_t)b * (size_t)(HH * WW);
    const int cq = c0a + 4 * q;                   // column of this quad

    // Row for sweep s: r = r0 + part + 4*(wid*2 + half + 8*s).
    // Slots 0..23 x parts 0..3 cover nr <= 96 rows (nr ~ 88-89 here).
    float acc = 0.0f;
    #pragma unroll
    for (int s = 0; s < 3; ++s) {
        const int r = e.r0 + part + 4 * (wid * 2 + half + 8 * s);
        if (r < e.r1 && q < nq) {
            const float4 v = *reinterpret_cast<const float4*>(
                xc + (size_t)r * WW + cq);
            acc += (cq     >= e.c0 && cq     < e.c1) ? v.x : 0.0f;
            acc += (cq + 1 >= e.c0 && cq + 1 < e.c1) ? v.y : 0.0f;
            acc += (cq + 2 >= e.c0 && cq + 2 < e.c1) ? v.z : 0.0f;
            acc += (cq + 3 >= e.c0 && cq + 3 < e.c1) ? v.w : 0.0f;
        }
    }
    // Safety tail for windows taller than 96 rows (dead for this region).
    for (int slot = wid * 2 + half + 24;
         e.r0 + part + 4 * slot < e.r1; slot += 8) {
        const int r = e.r0 + part + 4 * slot;
        if (q < nq) {
            const float4 v = *reinterpret_cast<const float4*>(
                xc + (size_t)r * WW + cq);
            acc += (cq     >= e.c0 && cq     < e.c1) ? v.x : 0.0f;
            acc += (cq + 1 >= e.c0 && cq + 1 < e.c1) ? v.y : 0.0f;
            acc += (cq + 2 >= e.c0 && cq + 2 < e.c1) ? v.z : 0.0f;
            acc += (cq + 3 >= e.c0 && cq + 3 < e.c1) ? v.w : 0.0f;
        }
    }

    #pragma unroll
    for (int off = 32; off > 0; off >>= 1)
        acc += __shfl_down(acc, off, 64);

    __shared__ float wsum[4];
    if (lane == 0) wsum[wid] = acc;
    __syncthreads();

    if (threadIdx.x == 0)
        ws[blk] = (wsum[0] + wsum[1]) + (wsum[2] + wsum[3]);
}

__global__ __launch_bounds__(64) void psroi_final_kernel(
    const float* __restrict__ region,
    const float* __restrict__ ws,
    float* __restrict__ out)
{
    const int t = threadIdx.x;
    float mean = 0.0f;
    if (t < KK * KK) {
        const int bi = t / KK;
        const int bj = t - bi * KK;
        const Ext e = bin_extent(region, bi, bj);
        const int n = (e.r1 - e.r0) * (e.c1 - e.c0);
        const float s = (ws[4 * t] + ws[4 * t + 1]) + (ws[4 * t + 2] + ws[4 * t + 3]);
        mean = s / (float)n;            // per-bin spatial mean
    }
    #pragma unroll
    for (int off = 32; off > 0; off >>= 1)
        mean += __shfl_down(mean, off, 64);
    if (t == 0) out[0] = mean / (float)(KK * KK);
}

extern "C" void kernel_launch(void* const* d_in, const int* in_sizes, int n_in,
                              void* d_out, int out_size, void* d_ws, size_t ws_size,
                              hipStream_t stream) {
    const float* x      = (const float*)d_in[0];   // (49, 1024, 1024) fp32
    const float* region = (const float*)d_in[1];   // (4,) fp32
    float* out = (float*)d_out;                    // scalar fp32
    float* ws  = (float*)d_ws;                     // uses 196 floats

    psroi_partial_kernel<<<KK * KK * 4, 256, 0, stream>>>(x, region, ws);
    psroi_final_kernel<<<1, 64, 0, stream>>>(region, ws, out);
}